// Round 4
// baseline (550.618 us; speedup 1.0000x reference)
//
#include <hip/hip_runtime.h>
#include <math.h>

// Problem constants
#define BB 2
#define SS 2048
#define EE 2048
#define HH 16
#define DD 128
#define FF 6144   // 3*E

typedef __attribute__((ext_vector_type(8))) short short8;
typedef __attribute__((ext_vector_type(4))) float floatx4;

static __device__ __forceinline__ unsigned short f2bf(float x) {
  unsigned u = __float_as_uint(x);
  u += 0x7fffu + ((u >> 16) & 1u);
  return (unsigned short)(u >> 16);
}
static __device__ __forceinline__ float bf2f(unsigned short h) {
  return __uint_as_float((unsigned)h << 16);
}

#define GLOAD_LDS16(gp, lp)                                       \
  __builtin_amdgcn_global_load_lds(                               \
      (const __attribute__((address_space(1))) void*)(gp),        \
      (__attribute__((address_space(3))) void*)(lp), 16, 0, 0)

// ---------------------------------------------------------------------------
// fp32 -> bf16 cast (float4 in, ushort4 out)
// ---------------------------------------------------------------------------
__global__ __launch_bounds__(256) void cast_f32_bf16(
    const float* __restrict__ in, unsigned short* __restrict__ out, int n4) {
  const int i = blockIdx.x * 256 + threadIdx.x;
  if (i >= n4) return;
  const float4 v = ((const float4*)in)[i];
  ushort4 o;
  o.x = f2bf(v.x); o.y = f2bf(v.y); o.z = f2bf(v.z); o.w = f2bf(v.w);
  ((ushort4*)out)[i] = o;
}

// ---------------------------------------------------------------------------
// bf16 MFMA GEMM (m97 structure): C[m][n] = sum_k A[m][k]*Bt[n][k] + bias[n]
// ---------------------------------------------------------------------------
static __device__ __forceinline__ void store_out(float* p, float v) { *p = v; }
static __device__ __forceinline__ void store_out(unsigned short* p, float v) {
  *p = f2bf(v);
}

template <typename OutT>
__global__ __launch_bounds__(256) void gemm_bf16_mfma(
    const unsigned short* __restrict__ A, const unsigned short* __restrict__ Bt,
    const float* __restrict__ bias, OutT* __restrict__ C,
    int M, int N, int K) {
  __shared__ unsigned short As[128][32];
  __shared__ unsigned short Bs[128][32];
  const int tid = threadIdx.x;
  const int L = tid & 63;
  const int w = tid >> 6;
  const int m0 = blockIdx.y * 128;
  const int n0 = blockIdx.x * 128;

  const int i0 = w * 2;
  const int lrow = L >> 2;
  const int lcol = (L & 3) * 8;
  const size_t a_off0 = (size_t)(m0 + (i0 + 0) * 16 + lrow) * K + lcol;
  const size_t a_off1 = (size_t)(m0 + (i0 + 1) * 16 + lrow) * K + lcol;
  const size_t b_off0 = (size_t)(n0 + (i0 + 0) * 16 + lrow) * K + lcol;
  const size_t b_off1 = (size_t)(n0 + (i0 + 1) * 16 + lrow) * K + lcol;

  const int wr = (w >> 1) * 64;
  const int wc = (w & 1) * 64;
  const int lane16 = L & 15;
  const int quad = L >> 4;

  floatx4 acc[4][4] = {};

  for (int k0 = 0; k0 < K; k0 += 32) {
    __syncthreads();
    GLOAD_LDS16(A + a_off0 + k0, &As[(i0 + 0) * 16][0]);
    GLOAD_LDS16(A + a_off1 + k0, &As[(i0 + 1) * 16][0]);
    GLOAD_LDS16(Bt + b_off0 + k0, &Bs[(i0 + 0) * 16][0]);
    GLOAD_LDS16(Bt + b_off1 + k0, &Bs[(i0 + 1) * 16][0]);
    __syncthreads();

    short8 a[4], b[4];
#pragma unroll
    for (int mi = 0; mi < 4; ++mi)
      a[mi] = *(const short8*)(&As[wr + mi * 16 + lane16][quad * 8]);
#pragma unroll
    for (int ni = 0; ni < 4; ++ni)
      b[ni] = *(const short8*)(&Bs[wc + ni * 16 + lane16][quad * 8]);
#pragma unroll
    for (int mi = 0; mi < 4; ++mi)
#pragma unroll
      for (int ni = 0; ni < 4; ++ni)
        acc[mi][ni] = __builtin_amdgcn_mfma_f32_16x16x32_bf16(
            a[mi], b[ni], acc[mi][ni], 0, 0, 0);
  }

#pragma unroll
  for (int ni = 0; ni < 4; ++ni) {
    const int col = n0 + wc + ni * 16 + lane16;
    const float bv = bias[col];
#pragma unroll
    for (int mi = 0; mi < 4; ++mi) {
      const int row = m0 + wr + mi * 16 + quad * 4;
#pragma unroll
      for (int r = 0; r < 4; ++r)
        store_out(&C[(size_t)(row + r) * N + col], acc[mi][ni][r] + bv);
    }
  }
}

// ---------------------------------------------------------------------------
// Rotary on bf16 qkv in place. qkv layout [B][S][3][H][D] bf16.
// ---------------------------------------------------------------------------
__global__ __launch_bounds__(256) void rotary_kernel(unsigned short* __restrict__ qkv) {
  const int idx = blockIdx.x * blockDim.x + threadIdx.x;
  const int d = idx & 63;
  const int h = (idx >> 6) & (HH - 1);
  const int s = (idx >> 10) & (SS - 1);
  const int b = idx >> 21;

  const float inv_freq = powf(10000.0f, -(float)d / 64.0f);
  const float freq = (float)s * inv_freq;
  const float c = cosf(freq);
  const float sn = sinf(freq);

  const size_t base = ((size_t)b * SS + s) * FF + h * DD + d;
  unsigned short* q = qkv + base;
  unsigned short* k = qkv + base + EE;

  const float q1 = bf2f(q[0]), q2 = bf2f(q[64]);
  q[0]  = f2bf(q1 * c - q2 * sn);
  q[64] = f2bf(q2 * c + q1 * sn);
  const float k1 = bf2f(k[0]), k2 = bf2f(k[64]);
  k[0]  = f2bf(k1 * c - k2 * sn);
  k[64] = f2bf(k2 * c + k1 * sn);
}

// ---------------------------------------------------------------------------
// V transpose: qkv V slab [b][s][h][d] -> vt [b*H+h][d][s]   (bf16)
// ---------------------------------------------------------------------------
__global__ __launch_bounds__(256) void transpose_v(
    const unsigned short* __restrict__ qkv, unsigned short* __restrict__ vt) {
  __shared__ unsigned short T[64][72];
  const int t = threadIdx.x;
  const int s0 = blockIdx.x * 64;
  const int d0 = blockIdx.y * 64;
  const int bh = blockIdx.z;
  const int b = bh >> 4, h = bh & 15;
  {
    const int r = t >> 2, c = (t & 3) * 16;
    const unsigned short* src =
        qkv + ((size_t)b * SS + s0 + r) * FF + 2 * EE + h * DD + d0 + c;
    const uint4 u0 = *(const uint4*)src;
    const uint4 u1 = *(const uint4*)(src + 8);
    *(uint4*)&T[r][c] = u0;
    *(uint4*)&T[r][c + 8] = u1;
  }
  __syncthreads();
  {
    const int rr = t >> 2, cc = (t & 3) * 16;
    unsigned short vals[16];
#pragma unroll
    for (int j = 0; j < 16; ++j) vals[j] = T[cc + j][rr];
    unsigned short* dst =
        vt + (size_t)bh * DD * SS + (size_t)(d0 + rr) * SS + s0 + cc;
    *(uint4*)dst = *(uint4*)&vals[0];
    *(uint4*)(dst + 8) = *(uint4*)&vals[8];
  }
}

// ---------------------------------------------------------------------------
// MFMA flash attention, causal — S^T / O^T orientation.
// Block: 128 q rows (4 waves x 32 q), K tiles of 64 kk.
// QK^T computed as S^T = K x Q^T (mfma(kf, qf)): C row=kk, col=q=lane16.
// Softmax per-column: 16 local values + 2 shuffles (xor 16, 32).
// P packed b64 into Ssh[q][kk] (wave-private rows, no barrier needed).
// PV computed as O^T = V^T x P^T (mfma(vf, pa)): C row=d, col=q=lane16,
// so alpha rescale is per-lane and epilogue stores are d-contiguous b64.
// LDS: 16KB K + 16KB Vt + 18KB P = 50KB -> 3 blocks/CU.
// ---------------------------------------------------------------------------
#define ATQ 128
#define ATK 64

__global__ __launch_bounds__(256, 3) void attn_mfma(
    const unsigned short* __restrict__ qkv,
    const unsigned short* __restrict__ vt,
    unsigned short* __restrict__ ctx) {
  __shared__ __align__(16) unsigned short Ksh[64 * 128];
  __shared__ __align__(16) unsigned short Vsh[128 * 64];
  __shared__ __align__(16) unsigned short Ssh[128][72];

  const int tid = threadIdx.x;
  const int L = tid & 63;
  const int w = tid >> 6;
  const int lane16 = L & 15;
  const int quad = L >> 4;

  const int qb = (int)gridDim.x - 1 - (int)blockIdx.x;  // longest blocks first
  const int h = blockIdx.y;
  const int b = blockIdx.z;
  const int q0 = qb * ATQ;
  const int bh = b * HH + h;
  const float scale = 0.08838834764831845f;  // 1/sqrt(128)

  // Q frags (B-operand): lane holds Q[q = w*32+mi*16+lane16][d = dc*32+quad*8+j]
  short8 qf[2][4];
#pragma unroll
  for (int mi = 0; mi < 2; ++mi) {
    const int q = q0 + w * 32 + mi * 16 + lane16;
    const unsigned short* qp = qkv + ((size_t)b * SS + q) * FF + h * DD + quad * 8;
#pragma unroll
    for (int dc = 0; dc < 4; ++dc)
      qf[mi][dc] = *(const short8*)(qp + dc * 32);
  }

  // Staging address precompute (XOR-swizzled 16B chunks, as before).
  size_t koff[4];
  size_t voff[4];
#pragma unroll
  for (int j = 0; j < 4; ++j) {
    const int kk = (w * 4 + j) * 4 + quad;
    const int cgk = lane16 ^ (kk & 15);
    koff[j] = ((size_t)b * SS + kk) * FF + EE + h * DD + cgk * 8;
    const int d = (w * 4 + j) * 8 + (L >> 3);
    const int cgv = (L & 7) ^ (L >> 3);
    voff[j] = (size_t)bh * DD * SS + (size_t)d * SS + cgv * 8;
  }

  // O^T accumulator: acc[dt][mi], C row = d = dt*16+quad*4+r, col = q = lane16
  floatx4 acc[8][2] = {};
  float m_i[2], l_i[2];
#pragma unroll
  for (int mi = 0; mi < 2; ++mi) { m_i[mi] = -3.0e38f; l_i[mi] = 0.0f; }

  const int nkt = (q0 + ATQ) / ATK;
  for (int kt = 0; kt < nkt; ++kt) {
    const int k0 = kt * ATK;
    __syncthreads();
#pragma unroll
    for (int j = 0; j < 4; ++j) {
      GLOAD_LDS16(qkv + koff[j] + (size_t)k0 * FF, Ksh + (w * 4 + j) * 512);
      GLOAD_LDS16(vt + voff[j] + k0, Vsh + (w * 4 + j) * 512);
    }
    __syncthreads();

    // --- S^T = K x Q^T : per wave 64 kk x 32 q ---
    floatx4 st[4][2] = {};
#pragma unroll
    for (int kkt = 0; kkt < 4; ++kkt) {
      const int kk = kkt * 16 + lane16;
#pragma unroll
      for (int dc = 0; dc < 4; ++dc) {
        const int pos = (dc * 4 + quad) ^ lane16;
        const short8 kf = *(const short8*)(Ksh + kk * 128 + pos * 8);
#pragma unroll
        for (int mi = 0; mi < 2; ++mi)
          st[kkt][mi] = __builtin_amdgcn_mfma_f32_16x16x32_bf16(
              kf, qf[mi][dc], st[kkt][mi], 0, 0, 0);
      }
    }

    // --- scale + causal mask (row=kk=kkt*16+quad*4+r, col=q=mi*16+lane16) ---
    const bool needmask = (k0 + ATK - 1) > (q0 + w * 32);
#pragma unroll
    for (int mi = 0; mi < 2; ++mi) {
      const int q_glob = q0 + w * 32 + mi * 16 + lane16;
#pragma unroll
      for (int kkt = 0; kkt < 4; ++kkt) {
        const int kk_base = k0 + kkt * 16 + quad * 4;
#pragma unroll
        for (int r = 0; r < 4; ++r) {
          float v = st[kkt][mi][r] * scale;
          if (needmask && (kk_base + r) > q_glob) v = -3.0e38f;
          st[kkt][mi][r] = v;
        }
      }
    }

    // --- online softmax per column q (=lane16), reduce across quads ---
    float alpha[2];
#pragma unroll
    for (int mi = 0; mi < 2; ++mi) {
      float tm = -3.0e38f;
#pragma unroll
      for (int kkt = 0; kkt < 4; ++kkt)
#pragma unroll
        for (int r = 0; r < 4; ++r) tm = fmaxf(tm, st[kkt][mi][r]);
      tm = fmaxf(tm, __shfl_xor(tm, 16));
      tm = fmaxf(tm, __shfl_xor(tm, 32));
      const float mn = fmaxf(m_i[mi], tm);
      alpha[mi] = __expf(m_i[mi] - mn);
      m_i[mi] = mn;

      float rs = 0.0f;
#pragma unroll
      for (int kkt = 0; kkt < 4; ++kkt)
#pragma unroll
        for (int r = 0; r < 4; ++r) {
          const float p = __expf(st[kkt][mi][r] - mn);
          st[kkt][mi][r] = p;
          rs += p;
        }
      rs += __shfl_xor(rs, 16);
      rs += __shfl_xor(rs, 32);
      l_i[mi] = l_i[mi] * alpha[mi] + rs;

      // packed P write: 4 kk-contiguous bf16 per lane per kkt
#pragma unroll
      for (int kkt = 0; kkt < 4; ++kkt) {
        ushort4 pk;
        pk.x = f2bf(st[kkt][mi][0]);
        pk.y = f2bf(st[kkt][mi][1]);
        pk.z = f2bf(st[kkt][mi][2]);
        pk.w = f2bf(st[kkt][mi][3]);
        *(ushort4*)(&Ssh[w * 32 + mi * 16 + lane16][kkt * 16 + quad * 4]) = pk;
      }
    }

    // rescale O^T accumulator (alpha indexed by col q = lane16: per-lane)
#pragma unroll
    for (int dt = 0; dt < 8; ++dt)
#pragma unroll
      for (int mi = 0; mi < 2; ++mi)
#pragma unroll
        for (int r = 0; r < 4; ++r) acc[dt][mi][r] *= alpha[mi];

    // --- O^T += V^T x P^T : per wave 128 d x 32 q, contraction 64 kk ---
#pragma unroll
    for (int kc = 0; kc < 2; ++kc) {
      short8 pa[2];
#pragma unroll
      for (int mi = 0; mi < 2; ++mi)
        pa[mi] = *(const short8*)(&Ssh[w * 32 + mi * 16 + lane16][kc * 32 + quad * 8]);
#pragma unroll
      for (int dt = 0; dt < 8; ++dt) {
        const int d = dt * 16 + lane16;
        const int pos = (kc * 4 + quad) ^ (d & 7);
        const short8 vf = *(const short8*)(Vsh + d * 64 + pos * 8);
#pragma unroll
        for (int mi = 0; mi < 2; ++mi)
          acc[dt][mi] = __builtin_amdgcn_mfma_f32_16x16x32_bf16(
              vf, pa[mi], acc[dt][mi], 0, 0, 0);
      }
    }
  }

  // epilogue: O^T row=d=dt*16+quad*4+r, col=q=mi*16+lane16 -> ctx[q][h*128+d]
#pragma unroll
  for (int mi = 0; mi < 2; ++mi) {
    const float inv = 1.0f / l_i[mi];
    const int q = q0 + w * 32 + mi * 16 + lane16;
    unsigned short* op = ctx + ((size_t)b * SS + q) * EE + h * DD + quad * 4;
#pragma unroll
    for (int dt = 0; dt < 8; ++dt) {
      ushort4 o;
      o.x = f2bf(acc[dt][mi][0] * inv);
      o.y = f2bf(acc[dt][mi][1] * inv);
      o.z = f2bf(acc[dt][mi][2] * inv);
      o.w = f2bf(acc[dt][mi][3] * inv);
      *(ushort4*)(op + dt * 16) = o;
    }
  }
}

// ---------------------------------------------------------------------------
// Launch
// ---------------------------------------------------------------------------
extern "C" void kernel_launch(void* const* d_in, const int* in_sizes, int n_in,
                              void* d_out, int out_size, void* d_ws,
                              size_t ws_size, hipStream_t stream) {
  const float* x    = (const float*)d_in[0];
  const float* wqkv = (const float*)d_in[1];
  const float* bqkv = (const float*)d_in[2];
  const float* wout = (const float*)d_in[3];
  const float* bout = (const float*)d_in[4];
  float* out = (float*)d_out;

  unsigned short* qkvb = (unsigned short*)d_ws;      // 25165824 elems
  unsigned short* xb   = qkvb + (size_t)25165824;    //  8388608
  unsigned short* wqb  = xb + (size_t)8388608;       // 12582912
  unsigned short* ctxb = wqb + (size_t)12582912;     //  8388608
  unsigned short* wob  = ctxb + (size_t)8388608;     //  4194304
  unsigned short* vtb  = wob + (size_t)4194304;      //  8388608

  const int M = BB * SS;  // 4096

  cast_f32_bf16<<<8192, 256, 0, stream>>>(x, xb, 2097152);
  cast_f32_bf16<<<12288, 256, 0, stream>>>(wqkv, wqb, 3145728);
  cast_f32_bf16<<<4096, 256, 0, stream>>>(wout, wob, 1048576);

  {
    dim3 grid(FF / 128, M / 128);
    gemm_bf16_mfma<unsigned short><<<grid, 256, 0, stream>>>(
        xb, wqb, bqkv, qkvb, M, FF, EE);
  }
  {
    const int total = BB * SS * HH * 64;
    rotary_kernel<<<total / 256, 256, 0, stream>>>(qkvb);
  }
  {
    dim3 grid(SS / 64, DD / 64, BB * HH);
    transpose_v<<<grid, 256, 0, stream>>>(qkvb, vtb);
  }
  {
    dim3 grid(SS / ATQ, HH, BB);
    attn_mfma<<<grid, 256, 0, stream>>>(qkvb, vtb, ctxb);
  }
  {
    dim3 grid(EE / 128, M / 128);
    gemm_bf16_mfma<float><<<grid, 256, 0, stream>>>(
        ctxb, wob, bout, out, M, EE, EE);
  }
}

// Round 5
// 479.991 us; speedup vs baseline: 1.1471x; 1.1471x over previous
//
#include <hip/hip_runtime.h>
#include <math.h>

// Problem constants
#define BB 2
#define SS 2048
#define EE 2048
#define HH 16
#define DD 128
#define FF 6144   // 3*E

typedef __attribute__((ext_vector_type(8))) short short8;
typedef __attribute__((ext_vector_type(4))) float floatx4;

static __device__ __forceinline__ unsigned short f2bf(float x) {
  unsigned u = __float_as_uint(x);
  u += 0x7fffu + ((u >> 16) & 1u);
  return (unsigned short)(u >> 16);
}
static __device__ __forceinline__ float bf2f(unsigned short h) {
  return __uint_as_float((unsigned)h << 16);
}

#define GLOAD_LDS16(gp, lp)                                       \
  __builtin_amdgcn_global_load_lds(                               \
      (const __attribute__((address_space(1))) void*)(gp),        \
      (__attribute__((address_space(3))) void*)(lp), 16, 0, 0)

// ---------------------------------------------------------------------------
// fp32 -> bf16 cast (float4 in, ushort4 out)
// ---------------------------------------------------------------------------
__global__ __launch_bounds__(256) void cast_f32_bf16(
    const float* __restrict__ in, unsigned short* __restrict__ out, int n4) {
  const int i = blockIdx.x * 256 + threadIdx.x;
  if (i >= n4) return;
  const float4 v = ((const float4*)in)[i];
  ushort4 o;
  o.x = f2bf(v.x); o.y = f2bf(v.y); o.z = f2bf(v.z); o.w = f2bf(v.w);
  ((ushort4*)out)[i] = o;
}

// ---------------------------------------------------------------------------
// bf16 MFMA GEMM (m97 structure): C[m][n] = sum_k A[m][k]*Bt[n][k] + bias[n]
// ---------------------------------------------------------------------------
static __device__ __forceinline__ void store_out(float* p, float v) { *p = v; }
static __device__ __forceinline__ void store_out(unsigned short* p, float v) {
  *p = f2bf(v);
}

template <typename OutT>
__global__ __launch_bounds__(256) void gemm_bf16_mfma(
    const unsigned short* __restrict__ A, const unsigned short* __restrict__ Bt,
    const float* __restrict__ bias, OutT* __restrict__ C,
    int M, int N, int K) {
  __shared__ unsigned short As[128][32];
  __shared__ unsigned short Bs[128][32];
  const int tid = threadIdx.x;
  const int L = tid & 63;
  const int w = tid >> 6;
  const int m0 = blockIdx.y * 128;
  const int n0 = blockIdx.x * 128;

  const int i0 = w * 2;
  const int lrow = L >> 2;
  const int lcol = (L & 3) * 8;
  const size_t a_off0 = (size_t)(m0 + (i0 + 0) * 16 + lrow) * K + lcol;
  const size_t a_off1 = (size_t)(m0 + (i0 + 1) * 16 + lrow) * K + lcol;
  const size_t b_off0 = (size_t)(n0 + (i0 + 0) * 16 + lrow) * K + lcol;
  const size_t b_off1 = (size_t)(n0 + (i0 + 1) * 16 + lrow) * K + lcol;

  const int wr = (w >> 1) * 64;
  const int wc = (w & 1) * 64;
  const int lane16 = L & 15;
  const int quad = L >> 4;

  floatx4 acc[4][4] = {};

  for (int k0 = 0; k0 < K; k0 += 32) {
    __syncthreads();
    GLOAD_LDS16(A + a_off0 + k0, &As[(i0 + 0) * 16][0]);
    GLOAD_LDS16(A + a_off1 + k0, &As[(i0 + 1) * 16][0]);
    GLOAD_LDS16(Bt + b_off0 + k0, &Bs[(i0 + 0) * 16][0]);
    GLOAD_LDS16(Bt + b_off1 + k0, &Bs[(i0 + 1) * 16][0]);
    __syncthreads();

    short8 a[4], b[4];
#pragma unroll
    for (int mi = 0; mi < 4; ++mi)
      a[mi] = *(const short8*)(&As[wr + mi * 16 + lane16][quad * 8]);
#pragma unroll
    for (int ni = 0; ni < 4; ++ni)
      b[ni] = *(const short8*)(&Bs[wc + ni * 16 + lane16][quad * 8]);
#pragma unroll
    for (int mi = 0; mi < 4; ++mi)
#pragma unroll
      for (int ni = 0; ni < 4; ++ni)
        acc[mi][ni] = __builtin_amdgcn_mfma_f32_16x16x32_bf16(
            a[mi], b[ni], acc[mi][ni], 0, 0, 0);
  }

#pragma unroll
  for (int ni = 0; ni < 4; ++ni) {
    const int col = n0 + wc + ni * 16 + lane16;
    const float bv = bias[col];
#pragma unroll
    for (int mi = 0; mi < 4; ++mi) {
      const int row = m0 + wr + mi * 16 + quad * 4;
#pragma unroll
      for (int r = 0; r < 4; ++r)
        store_out(&C[(size_t)(row + r) * N + col], acc[mi][ni][r] + bv);
    }
  }
}

// ---------------------------------------------------------------------------
// Rotary on bf16 qkv in place. qkv layout [B][S][3][H][D] bf16.
// ---------------------------------------------------------------------------
__global__ __launch_bounds__(256) void rotary_kernel(unsigned short* __restrict__ qkv) {
  const int idx = blockIdx.x * blockDim.x + threadIdx.x;
  const int d = idx & 63;
  const int h = (idx >> 6) & (HH - 1);
  const int s = (idx >> 10) & (SS - 1);
  const int b = idx >> 21;

  const float inv_freq = powf(10000.0f, -(float)d / 64.0f);
  const float freq = (float)s * inv_freq;
  const float c = cosf(freq);
  const float sn = sinf(freq);

  const size_t base = ((size_t)b * SS + s) * FF + h * DD + d;
  unsigned short* q = qkv + base;
  unsigned short* k = qkv + base + EE;

  const float q1 = bf2f(q[0]), q2 = bf2f(q[64]);
  q[0]  = f2bf(q1 * c - q2 * sn);
  q[64] = f2bf(q2 * c + q1 * sn);
  const float k1 = bf2f(k[0]), k2 = bf2f(k[64]);
  k[0]  = f2bf(k1 * c - k2 * sn);
  k[64] = f2bf(k2 * c + k1 * sn);
}

// ---------------------------------------------------------------------------
// V transpose: qkv V slab [b][s][h][d] -> vt [b*H+h][d][s]   (bf16)
// ---------------------------------------------------------------------------
__global__ __launch_bounds__(256) void transpose_v(
    const unsigned short* __restrict__ qkv, unsigned short* __restrict__ vt) {
  __shared__ unsigned short T[64][72];
  const int t = threadIdx.x;
  const int s0 = blockIdx.x * 64;
  const int d0 = blockIdx.y * 64;
  const int bh = blockIdx.z;
  const int b = bh >> 4, h = bh & 15;
  {
    const int r = t >> 2, c = (t & 3) * 16;
    const unsigned short* src =
        qkv + ((size_t)b * SS + s0 + r) * FF + 2 * EE + h * DD + d0 + c;
    const uint4 u0 = *(const uint4*)src;
    const uint4 u1 = *(const uint4*)(src + 8);
    *(uint4*)&T[r][c] = u0;
    *(uint4*)&T[r][c + 8] = u1;
  }
  __syncthreads();
  {
    const int rr = t >> 2, cc = (t & 3) * 16;
    unsigned short vals[16];
#pragma unroll
    for (int j = 0; j < 16; ++j) vals[j] = T[cc + j][rr];
    unsigned short* dst =
        vt + (size_t)bh * DD * SS + (size_t)(d0 + rr) * SS + s0 + cc;
    *(uint4*)dst = *(uint4*)&vals[0];
    *(uint4*)(dst + 8) = *(uint4*)&vals[8];
  }
}

// ---------------------------------------------------------------------------
// MFMA flash attention, causal — S^T/O^T orientation + double-buffered K/V.
// Block: 128 q (4 waves x 32 q). K-tiles of 32 kk, two LDS buffers.
// Stage for tile t+1 is issued right AFTER the barrier that opens tile t,
// so the next barrier's vmcnt(0) drain finds those loads already complete
// (they age a full compute phase) — removes the m97-style barrier stall.
// Waves skip fully-masked diagonal tiles. LDS: 16K K + 16K V + 10K P = 42KB.
// ---------------------------------------------------------------------------
#define ATQ 128
#define ATK 32
#define SPAD 40  // P row stride (ushorts): 80 B, 16B-aligned, odd dword count

__global__ __launch_bounds__(256, 2) void attn_mfma(
    const unsigned short* __restrict__ qkv,
    const unsigned short* __restrict__ vt,
    unsigned short* __restrict__ ctx) {
  __shared__ __align__(16) unsigned short Ksh[2][ATK * DD];  // [buf][kk][d]
  __shared__ __align__(16) unsigned short Vsh[2][DD * ATK];  // [buf][d][kk]
  __shared__ __align__(16) unsigned short Ssh[ATQ][SPAD];    // P [q][kk]

  const int tid = threadIdx.x;
  const int L = tid & 63;
  const int w = tid >> 6;
  const int lane16 = L & 15;
  const int quad = L >> 4;

  const int qb = (int)gridDim.x - 1 - (int)blockIdx.x;  // longest first
  const int h = blockIdx.y;
  const int b = blockIdx.z;
  const int q0 = qb * ATQ;
  const int bh = b * HH + h;
  const float scale = 0.08838834764831845f;  // 1/sqrt(128)

  // Q frags (B-operand): lane holds Q[q0+w*32+mi*16+lane16][dc*32+quad*8+j]
  short8 qf[2][4];
#pragma unroll
  for (int mi = 0; mi < 2; ++mi) {
    const int q = q0 + w * 32 + mi * 16 + lane16;
    const unsigned short* qp =
        qkv + ((size_t)b * SS + q) * FF + h * DD + quad * 8;
#pragma unroll
    for (int dc = 0; dc < 4; ++dc) qf[mi][dc] = *(const short8*)(qp + dc * 32);
  }

  // Staging addresses. K tile: 512 16B-chunks, c = j*256+tid, row kk=c>>4,
  // swizzled col chunk cg = (c&15)^(kk&15). V tile: c=j*256+tid, row d=c>>2,
  // cg = (c&3)^(d&3). LDS dest = contiguous chunk order (wave-uniform+lane*16).
  size_t koff[2], voff[2];
  int kdst[2], vdst[2];
#pragma unroll
  for (int j = 0; j < 2; ++j) {
    const int ck = j * 256 + tid;
    const int kk = ck >> 4;
    const int cgk = (ck & 15) ^ (kk & 15);
    koff[j] = ((size_t)b * SS + kk) * FF + EE + h * DD + cgk * 8;
    kdst[j] = (j * 256 + w * 64) * 8;
    const int d = ck >> 2;
    const int cgv = (ck & 3) ^ (d & 3);
    voff[j] = (size_t)bh * DD * SS + (size_t)d * SS + cgv * 8;
    vdst[j] = kdst[j];
  }

  floatx4 acc[8][2] = {};  // O^T: row d=dt*16+quad*4+r, col q=mi*16+lane16
  float m_i[2] = {-3.0e38f, -3.0e38f};
  float l_i[2] = {0.0f, 0.0f};

  const int nkt = 4 * qb + 4;
  const int mykt = 4 * qb + w;  // last tile this wave computes

  // prologue: stage tile 0 -> buf 0
#pragma unroll
  for (int j = 0; j < 2; ++j) {
    GLOAD_LDS16(qkv + koff[j], &Ksh[0][kdst[j]]);
    GLOAD_LDS16(vt + voff[j], &Vsh[0][vdst[j]]);
  }

  for (int kt = 0; kt < nkt; ++kt) {
    const int cur = kt & 1;
    __syncthreads();  // drains stage(kt) (issued one compute-phase ago)
    if (kt + 1 < nkt) {
      const size_t ka = (size_t)(kt + 1) * ATK * FF;
      const int va = (kt + 1) * ATK;
#pragma unroll
      for (int j = 0; j < 2; ++j) {
        GLOAD_LDS16(qkv + koff[j] + ka, &Ksh[cur ^ 1][kdst[j]]);
        GLOAD_LDS16(vt + voff[j] + va, &Vsh[cur ^ 1][vdst[j]]);
      }
    }
    if (kt > mykt) continue;  // fully-masked diagonal tile for this wave
    const int k0 = kt * ATK;
    const unsigned short* Kc = Ksh[cur];
    const unsigned short* Vc = Vsh[cur];

    // --- S^T = K x Q^T : 32 kk x 32 q per wave ---
    floatx4 st[2][2] = {};
#pragma unroll
    for (int kkt = 0; kkt < 2; ++kkt) {
      const unsigned short* krow = Kc + (kkt * 16 + lane16) * 128;
#pragma unroll
      for (int dc = 0; dc < 4; ++dc) {
        const short8 kf =
            *(const short8*)(krow + ((dc * 4 + quad) ^ lane16) * 8);
#pragma unroll
        for (int mi = 0; mi < 2; ++mi)
          st[kkt][mi] = __builtin_amdgcn_mfma_f32_16x16x32_bf16(
              kf, qf[mi][dc], st[kkt][mi], 0, 0, 0);
      }
    }

    // --- scale + causal mask (only diagonal tile needs it) ---
    const bool needmask = (kt == mykt);
#pragma unroll
    for (int mi = 0; mi < 2; ++mi) {
      const int q_glob = q0 + w * 32 + mi * 16 + lane16;
#pragma unroll
      for (int kkt = 0; kkt < 2; ++kkt) {
        const int kkb = k0 + kkt * 16 + quad * 4;
#pragma unroll
        for (int r = 0; r < 4; ++r) {
          float v = st[kkt][mi][r] * scale;
          if (needmask && (kkb + r) > q_glob) v = -3.0e38f;
          st[kkt][mi][r] = v;
        }
      }
    }

    // --- online softmax per column q: 8 local values + 2 shuffles ---
    float alpha[2];
#pragma unroll
    for (int mi = 0; mi < 2; ++mi) {
      float tm = -3.0e38f;
#pragma unroll
      for (int kkt = 0; kkt < 2; ++kkt)
#pragma unroll
        for (int r = 0; r < 4; ++r) tm = fmaxf(tm, st[kkt][mi][r]);
      tm = fmaxf(tm, __shfl_xor(tm, 16));
      tm = fmaxf(tm, __shfl_xor(tm, 32));
      const float mn = fmaxf(m_i[mi], tm);
      alpha[mi] = __expf(m_i[mi] - mn);
      m_i[mi] = mn;

      float rs = 0.0f;
#pragma unroll
      for (int kkt = 0; kkt < 2; ++kkt)
#pragma unroll
        for (int r = 0; r < 4; ++r) {
          const float p = __expf(st[kkt][mi][r] - mn);
          st[kkt][mi][r] = p;
          rs += p;
        }
      rs += __shfl_xor(rs, 16);
      rs += __shfl_xor(rs, 32);
      l_i[mi] = l_i[mi] * alpha[mi] + rs;

      // packed P write (wave-private rows; no barrier needed)
#pragma unroll
      for (int kkt = 0; kkt < 2; ++kkt) {
        ushort4 pk;
        pk.x = f2bf(st[kkt][mi][0]);
        pk.y = f2bf(st[kkt][mi][1]);
        pk.z = f2bf(st[kkt][mi][2]);
        pk.w = f2bf(st[kkt][mi][3]);
        *(ushort4*)(&Ssh[w * 32 + mi * 16 + lane16][kkt * 16 + quad * 4]) = pk;
      }
    }

    // rescale O^T (alpha is per-lane: col q = lane16)
#pragma unroll
    for (int dt = 0; dt < 8; ++dt)
#pragma unroll
      for (int mi = 0; mi < 2; ++mi)
#pragma unroll
        for (int r = 0; r < 4; ++r) acc[dt][mi][r] *= alpha[mi];

    // --- O^T += V^T x P^T : 128 d x 32 q, contraction 32 kk ---
    short8 pa[2];
#pragma unroll
    for (int mi = 0; mi < 2; ++mi)
      pa[mi] = *(const short8*)(&Ssh[w * 32 + mi * 16 + lane16][quad * 8]);
    const int vpos = (quad ^ (lane16 & 3)) * 8;
#pragma unroll
    for (int dt = 0; dt < 8; ++dt) {
      const short8 vf = *(const short8*)(Vc + (dt * 16 + lane16) * 32 + vpos);
#pragma unroll
      for (int mi = 0; mi < 2; ++mi)
        acc[dt][mi] = __builtin_amdgcn_mfma_f32_16x16x32_bf16(
            vf, pa[mi], acc[dt][mi], 0, 0, 0);
    }
  }

  // epilogue: O^T row=d=dt*16+quad*4+r, col=q=mi*16+lane16 -> ctx[q][h*128+d]
#pragma unroll
  for (int mi = 0; mi < 2; ++mi) {
    const float inv = 1.0f / l_i[mi];
    const int q = q0 + w * 32 + mi * 16 + lane16;
    unsigned short* op = ctx + ((size_t)b * SS + q) * EE + h * DD + quad * 4;
#pragma unroll
    for (int dt = 0; dt < 8; ++dt) {
      ushort4 o;
      o.x = f2bf(acc[dt][mi][0] * inv);
      o.y = f2bf(acc[dt][mi][1] * inv);
      o.z = f2bf(acc[dt][mi][2] * inv);
      o.w = f2bf(acc[dt][mi][3] * inv);
      *(ushort4*)(op + dt * 16) = o;
    }
  }
}

// ---------------------------------------------------------------------------
// Launch
// ---------------------------------------------------------------------------
extern "C" void kernel_launch(void* const* d_in, const int* in_sizes, int n_in,
                              void* d_out, int out_size, void* d_ws,
                              size_t ws_size, hipStream_t stream) {
  const float* x    = (const float*)d_in[0];
  const float* wqkv = (const float*)d_in[1];
  const float* bqkv = (const float*)d_in[2];
  const float* wout = (const float*)d_in[3];
  const float* bout = (const float*)d_in[4];
  float* out = (float*)d_out;

  unsigned short* qkvb = (unsigned short*)d_ws;      // 25165824 elems
  unsigned short* xb   = qkvb + (size_t)25165824;    //  8388608
  unsigned short* wqb  = xb + (size_t)8388608;       // 12582912
  unsigned short* ctxb = wqb + (size_t)12582912;     //  8388608
  unsigned short* wob  = ctxb + (size_t)8388608;     //  4194304
  unsigned short* vtb  = wob + (size_t)4194304;      //  8388608

  const int M = BB * SS;  // 4096

  cast_f32_bf16<<<8192, 256, 0, stream>>>(x, xb, 2097152);
  cast_f32_bf16<<<12288, 256, 0, stream>>>(wqkv, wqb, 3145728);
  cast_f32_bf16<<<4096, 256, 0, stream>>>(wout, wob, 1048576);

  {
    dim3 grid(FF / 128, M / 128);
    gemm_bf16_mfma<unsigned short><<<grid, 256, 0, stream>>>(
        xb, wqb, bqkv, qkvb, M, FF, EE);
  }
  {
    const int total = BB * SS * HH * 64;
    rotary_kernel<<<total / 256, 256, 0, stream>>>(qkvb);
  }
  {
    dim3 grid(SS / 64, DD / 64, BB * HH);
    transpose_v<<<grid, 256, 0, stream>>>(qkvb, vtb);
  }
  {
    dim3 grid(SS / ATQ, HH, BB);
    attn_mfma<<<grid, 256, 0, stream>>>(qkvb, vtb, ctxb);
  }
  {
    dim3 grid(EE / 128, M / 128);
    gemm_bf16_mfma<float><<<grid, 256, 0, stream>>>(
        ctxb, wob, bout, out, M, EE, EE);
  }
}

// Round 6
// 458.981 us; speedup vs baseline: 1.1997x; 1.0458x over previous
//
#include <hip/hip_runtime.h>
#include <math.h>

// Problem constants
#define BB 2
#define SS 2048
#define EE 2048
#define HH 16
#define DD 128
#define FF 6144   // 3*E

typedef __attribute__((ext_vector_type(8))) short short8;
typedef __attribute__((ext_vector_type(4))) float floatx4;

static __device__ __forceinline__ unsigned short f2bf(float x) {
  unsigned u = __float_as_uint(x);
  u += 0x7fffu + ((u >> 16) & 1u);
  return (unsigned short)(u >> 16);
}
static __device__ __forceinline__ float bf2f(unsigned short h) {
  return __uint_as_float((unsigned)h << 16);
}

#define GLOAD_LDS16(gp, lp)                                       \
  __builtin_amdgcn_global_load_lds(                               \
      (const __attribute__((address_space(1))) void*)(gp),        \
      (__attribute__((address_space(3))) void*)(lp), 16, 0, 0)

// ---------------------------------------------------------------------------
// fp32 -> bf16 cast (float4 in, ushort4 out)
// ---------------------------------------------------------------------------
__global__ __launch_bounds__(256) void cast_f32_bf16(
    const float* __restrict__ in, unsigned short* __restrict__ out, int n4) {
  const int i = blockIdx.x * 256 + threadIdx.x;
  if (i >= n4) return;
  const float4 v = ((const float4*)in)[i];
  ushort4 o;
  o.x = f2bf(v.x); o.y = f2bf(v.y); o.z = f2bf(v.z); o.w = f2bf(v.w);
  ((ushort4*)out)[i] = o;
}

// ---------------------------------------------------------------------------
// bf16 MFMA GEMM, double-buffered: C[m][n] = sum_k A[m][k]*Bt[n][k] + bias[n]
// 128x128 tile, BK=32, 256 threads = 4 waves, each wave 64x64 (4x4 frags of
// 16x16x32). One barrier per K-slab: stage slab k+1 right after the barrier
// that opens slab k, so the next barrier's vmcnt(0) drain finds aged loads.
// LDS: 2 x (8K A + 8K B) = 32 KB.
// ---------------------------------------------------------------------------
static __device__ __forceinline__ void store_out(float* p, float v) { *p = v; }
static __device__ __forceinline__ void store_out(unsigned short* p, float v) {
  *p = f2bf(v);
}

template <typename OutT>
__global__ __launch_bounds__(256) void gemm_bf16_mfma(
    const unsigned short* __restrict__ A, const unsigned short* __restrict__ Bt,
    const float* __restrict__ bias, OutT* __restrict__ C,
    int M, int N, int K) {
  __shared__ unsigned short As[2][128][32];
  __shared__ unsigned short Bs[2][128][32];
  const int tid = threadIdx.x;
  const int L = tid & 63;
  const int w = tid >> 6;
  const int m0 = blockIdx.y * 128;
  const int n0 = blockIdx.x * 128;

  const int i0 = w * 2;
  const int lrow = L >> 2;
  const int lcol = (L & 3) * 8;
  const size_t a_off0 = (size_t)(m0 + (i0 + 0) * 16 + lrow) * K + lcol;
  const size_t a_off1 = (size_t)(m0 + (i0 + 1) * 16 + lrow) * K + lcol;
  const size_t b_off0 = (size_t)(n0 + (i0 + 0) * 16 + lrow) * K + lcol;
  const size_t b_off1 = (size_t)(n0 + (i0 + 1) * 16 + lrow) * K + lcol;

  const int wr = (w >> 1) * 64;
  const int wc = (w & 1) * 64;
  const int lane16 = L & 15;
  const int quad = L >> 4;

  floatx4 acc[4][4] = {};

  // prologue: stage slab 0 -> buf 0
  GLOAD_LDS16(A + a_off0, &As[0][(i0 + 0) * 16][0]);
  GLOAD_LDS16(A + a_off1, &As[0][(i0 + 1) * 16][0]);
  GLOAD_LDS16(Bt + b_off0, &Bs[0][(i0 + 0) * 16][0]);
  GLOAD_LDS16(Bt + b_off1, &Bs[0][(i0 + 1) * 16][0]);

  for (int k0 = 0; k0 < K; k0 += 32) {
    const int cur = (k0 >> 5) & 1;
    __syncthreads();  // drains stage(k0) — issued one compute-phase ago
    if (k0 + 32 < K) {
      const int nxt = cur ^ 1;
      GLOAD_LDS16(A + a_off0 + k0 + 32, &As[nxt][(i0 + 0) * 16][0]);
      GLOAD_LDS16(A + a_off1 + k0 + 32, &As[nxt][(i0 + 1) * 16][0]);
      GLOAD_LDS16(Bt + b_off0 + k0 + 32, &Bs[nxt][(i0 + 0) * 16][0]);
      GLOAD_LDS16(Bt + b_off1 + k0 + 32, &Bs[nxt][(i0 + 1) * 16][0]);
    }

    short8 a[4], b[4];
#pragma unroll
    for (int mi = 0; mi < 4; ++mi)
      a[mi] = *(const short8*)(&As[cur][wr + mi * 16 + lane16][quad * 8]);
#pragma unroll
    for (int ni = 0; ni < 4; ++ni)
      b[ni] = *(const short8*)(&Bs[cur][wc + ni * 16 + lane16][quad * 8]);
#pragma unroll
    for (int mi = 0; mi < 4; ++mi)
#pragma unroll
      for (int ni = 0; ni < 4; ++ni)
        acc[mi][ni] = __builtin_amdgcn_mfma_f32_16x16x32_bf16(
            a[mi], b[ni], acc[mi][ni], 0, 0, 0);
  }

#pragma unroll
  for (int ni = 0; ni < 4; ++ni) {
    const int col = n0 + wc + ni * 16 + lane16;
    const float bv = bias[col];
#pragma unroll
    for (int mi = 0; mi < 4; ++mi) {
      const int row = m0 + wr + mi * 16 + quad * 4;
#pragma unroll
      for (int r = 0; r < 4; ++r)
        store_out(&C[(size_t)(row + r) * N + col], acc[mi][ni][r] + bv);
    }
  }
}

// ---------------------------------------------------------------------------
// Rotary on bf16 qkv in place. qkv layout [B][S][3][H][D] bf16.
// ---------------------------------------------------------------------------
__global__ __launch_bounds__(256) void rotary_kernel(unsigned short* __restrict__ qkv) {
  const int idx = blockIdx.x * blockDim.x + threadIdx.x;
  const int d = idx & 63;
  const int h = (idx >> 6) & (HH - 1);
  const int s = (idx >> 10) & (SS - 1);
  const int b = idx >> 21;

  const float inv_freq = powf(10000.0f, -(float)d / 64.0f);
  const float freq = (float)s * inv_freq;
  const float c = cosf(freq);
  const float sn = sinf(freq);

  const size_t base = ((size_t)b * SS + s) * FF + h * DD + d;
  unsigned short* q = qkv + base;
  unsigned short* k = qkv + base + EE;

  const float q1 = bf2f(q[0]), q2 = bf2f(q[64]);
  q[0]  = f2bf(q1 * c - q2 * sn);
  q[64] = f2bf(q2 * c + q1 * sn);
  const float k1 = bf2f(k[0]), k2 = bf2f(k[64]);
  k[0]  = f2bf(k1 * c - k2 * sn);
  k[64] = f2bf(k2 * c + k1 * sn);
}

// ---------------------------------------------------------------------------
// V transpose: qkv V slab [b][s][h][d] -> vt [b*H+h][d][s]   (bf16)
// ---------------------------------------------------------------------------
__global__ __launch_bounds__(256) void transpose_v(
    const unsigned short* __restrict__ qkv, unsigned short* __restrict__ vt) {
  __shared__ unsigned short T[64][72];
  const int t = threadIdx.x;
  const int s0 = blockIdx.x * 64;
  const int d0 = blockIdx.y * 64;
  const int bh = blockIdx.z;
  const int b = bh >> 4, h = bh & 15;
  {
    const int r = t >> 2, c = (t & 3) * 16;
    const unsigned short* src =
        qkv + ((size_t)b * SS + s0 + r) * FF + 2 * EE + h * DD + d0 + c;
    const uint4 u0 = *(const uint4*)src;
    const uint4 u1 = *(const uint4*)(src + 8);
    *(uint4*)&T[r][c] = u0;
    *(uint4*)&T[r][c + 8] = u1;
  }
  __syncthreads();
  {
    const int rr = t >> 2, cc = (t & 3) * 16;
    unsigned short vals[16];
#pragma unroll
    for (int j = 0; j < 16; ++j) vals[j] = T[cc + j][rr];
    unsigned short* dst =
        vt + (size_t)bh * DD * SS + (size_t)(d0 + rr) * SS + s0 + cc;
    *(uint4*)dst = *(uint4*)&vals[0];
    *(uint4*)(dst + 8) = *(uint4*)&vals[8];
  }
}

// ---------------------------------------------------------------------------
// MFMA flash attention, causal — S^T/O^T orientation + double-buffered K/V.
// (unchanged from R5)
// ---------------------------------------------------------------------------
#define ATQ 128
#define ATK 32
#define SPAD 40  // P row stride (ushorts): 80 B, 16B-aligned

__global__ __launch_bounds__(256, 2) void attn_mfma(
    const unsigned short* __restrict__ qkv,
    const unsigned short* __restrict__ vt,
    unsigned short* __restrict__ ctx) {
  __shared__ __align__(16) unsigned short Ksh[2][ATK * DD];  // [buf][kk][d]
  __shared__ __align__(16) unsigned short Vsh[2][DD * ATK];  // [buf][d][kk]
  __shared__ __align__(16) unsigned short Ssh[ATQ][SPAD];    // P [q][kk]

  const int tid = threadIdx.x;
  const int L = tid & 63;
  const int w = tid >> 6;
  const int lane16 = L & 15;
  const int quad = L >> 4;

  const int qb = (int)gridDim.x - 1 - (int)blockIdx.x;  // longest first
  const int h = blockIdx.y;
  const int b = blockIdx.z;
  const int q0 = qb * ATQ;
  const int bh = b * HH + h;
  const float scale = 0.08838834764831845f;  // 1/sqrt(128)

  short8 qf[2][4];
#pragma unroll
  for (int mi = 0; mi < 2; ++mi) {
    const int q = q0 + w * 32 + mi * 16 + lane16;
    const unsigned short* qp =
        qkv + ((size_t)b * SS + q) * FF + h * DD + quad * 8;
#pragma unroll
    for (int dc = 0; dc < 4; ++dc) qf[mi][dc] = *(const short8*)(qp + dc * 32);
  }

  size_t koff[2], voff[2];
  int kdst[2], vdst[2];
#pragma unroll
  for (int j = 0; j < 2; ++j) {
    const int ck = j * 256 + tid;
    const int kk = ck >> 4;
    const int cgk = (ck & 15) ^ (kk & 15);
    koff[j] = ((size_t)b * SS + kk) * FF + EE + h * DD + cgk * 8;
    kdst[j] = (j * 256 + w * 64) * 8;
    const int d = ck >> 2;
    const int cgv = (ck & 3) ^ (d & 3);
    voff[j] = (size_t)bh * DD * SS + (size_t)d * SS + cgv * 8;
    vdst[j] = kdst[j];
  }

  floatx4 acc[8][2] = {};  // O^T: row d=dt*16+quad*4+r, col q=mi*16+lane16
  float m_i[2] = {-3.0e38f, -3.0e38f};
  float l_i[2] = {0.0f, 0.0f};

  const int nkt = 4 * qb + 4;
  const int mykt = 4 * qb + w;

#pragma unroll
  for (int j = 0; j < 2; ++j) {
    GLOAD_LDS16(qkv + koff[j], &Ksh[0][kdst[j]]);
    GLOAD_LDS16(vt + voff[j], &Vsh[0][vdst[j]]);
  }

  for (int kt = 0; kt < nkt; ++kt) {
    const int cur = kt & 1;
    __syncthreads();
    if (kt + 1 < nkt) {
      const size_t ka = (size_t)(kt + 1) * ATK * FF;
      const int va = (kt + 1) * ATK;
#pragma unroll
      for (int j = 0; j < 2; ++j) {
        GLOAD_LDS16(qkv + koff[j] + ka, &Ksh[cur ^ 1][kdst[j]]);
        GLOAD_LDS16(vt + voff[j] + va, &Vsh[cur ^ 1][vdst[j]]);
      }
    }
    if (kt > mykt) continue;
    const int k0 = kt * ATK;
    const unsigned short* Kc = Ksh[cur];
    const unsigned short* Vc = Vsh[cur];

    floatx4 st[2][2] = {};
#pragma unroll
    for (int kkt = 0; kkt < 2; ++kkt) {
      const unsigned short* krow = Kc + (kkt * 16 + lane16) * 128;
#pragma unroll
      for (int dc = 0; dc < 4; ++dc) {
        const short8 kf =
            *(const short8*)(krow + ((dc * 4 + quad) ^ lane16) * 8);
#pragma unroll
        for (int mi = 0; mi < 2; ++mi)
          st[kkt][mi] = __builtin_amdgcn_mfma_f32_16x16x32_bf16(
              kf, qf[mi][dc], st[kkt][mi], 0, 0, 0);
      }
    }

    const bool needmask = (kt == mykt);
#pragma unroll
    for (int mi = 0; mi < 2; ++mi) {
      const int q_glob = q0 + w * 32 + mi * 16 + lane16;
#pragma unroll
      for (int kkt = 0; kkt < 2; ++kkt) {
        const int kkb = k0 + kkt * 16 + quad * 4;
#pragma unroll
        for (int r = 0; r < 4; ++r) {
          float v = st[kkt][mi][r] * scale;
          if (needmask && (kkb + r) > q_glob) v = -3.0e38f;
          st[kkt][mi][r] = v;
        }
      }
    }

    float alpha[2];
#pragma unroll
    for (int mi = 0; mi < 2; ++mi) {
      float tm = -3.0e38f;
#pragma unroll
      for (int kkt = 0; kkt < 2; ++kkt)
#pragma unroll
        for (int r = 0; r < 4; ++r) tm = fmaxf(tm, st[kkt][mi][r]);
      tm = fmaxf(tm, __shfl_xor(tm, 16));
      tm = fmaxf(tm, __shfl_xor(tm, 32));
      const float mn = fmaxf(m_i[mi], tm);
      alpha[mi] = __expf(m_i[mi] - mn);
      m_i[mi] = mn;

      float rs = 0.0f;
#pragma unroll
      for (int kkt = 0; kkt < 2; ++kkt)
#pragma unroll
        for (int r = 0; r < 4; ++r) {
          const float p = __expf(st[kkt][mi][r] - mn);
          st[kkt][mi][r] = p;
          rs += p;
        }
      rs += __shfl_xor(rs, 16);
      rs += __shfl_xor(rs, 32);
      l_i[mi] = l_i[mi] * alpha[mi] + rs;

#pragma unroll
      for (int kkt = 0; kkt < 2; ++kkt) {
        ushort4 pk;
        pk.x = f2bf(st[kkt][mi][0]);
        pk.y = f2bf(st[kkt][mi][1]);
        pk.z = f2bf(st[kkt][mi][2]);
        pk.w = f2bf(st[kkt][mi][3]);
        *(ushort4*)(&Ssh[w * 32 + mi * 16 + lane16][kkt * 16 + quad * 4]) = pk;
      }
    }

#pragma unroll
    for (int dt = 0; dt < 8; ++dt)
#pragma unroll
      for (int mi = 0; mi < 2; ++mi)
#pragma unroll
        for (int r = 0; r < 4; ++r) acc[dt][mi][r] *= alpha[mi];

    short8 pa[2];
#pragma unroll
    for (int mi = 0; mi < 2; ++mi)
      pa[mi] = *(const short8*)(&Ssh[w * 32 + mi * 16 + lane16][quad * 8]);
    const int vpos = (quad ^ (lane16 & 3)) * 8;
#pragma unroll
    for (int dt = 0; dt < 8; ++dt) {
      const short8 vf = *(const short8*)(Vc + (dt * 16 + lane16) * 32 + vpos);
#pragma unroll
      for (int mi = 0; mi < 2; ++mi)
        acc[dt][mi] = __builtin_amdgcn_mfma_f32_16x16x32_bf16(
            vf, pa[mi], acc[dt][mi], 0, 0, 0);
    }
  }

#pragma unroll
  for (int mi = 0; mi < 2; ++mi) {
    const float inv = 1.0f / l_i[mi];
    const int q = q0 + w * 32 + mi * 16 + lane16;
    unsigned short* op = ctx + ((size_t)b * SS + q) * EE + h * DD + quad * 4;
#pragma unroll
    for (int dt = 0; dt < 8; ++dt) {
      ushort4 o;
      o.x = f2bf(acc[dt][mi][0] * inv);
      o.y = f2bf(acc[dt][mi][1] * inv);
      o.z = f2bf(acc[dt][mi][2] * inv);
      o.w = f2bf(acc[dt][mi][3] * inv);
      *(ushort4*)(op + dt * 16) = o;
    }
  }
}

// ---------------------------------------------------------------------------
// Launch
// ---------------------------------------------------------------------------
extern "C" void kernel_launch(void* const* d_in, const int* in_sizes, int n_in,
                              void* d_out, int out_size, void* d_ws,
                              size_t ws_size, hipStream_t stream) {
  const float* x    = (const float*)d_in[0];
  const float* wqkv = (const float*)d_in[1];
  const float* bqkv = (const float*)d_in[2];
  const float* wout = (const float*)d_in[3];
  const float* bout = (const float*)d_in[4];
  float* out = (float*)d_out;

  unsigned short* qkvb = (unsigned short*)d_ws;      // 25165824 elems
  unsigned short* xb   = qkvb + (size_t)25165824;    //  8388608
  unsigned short* wqb  = xb + (size_t)8388608;       // 12582912
  unsigned short* ctxb = wqb + (size_t)12582912;     //  8388608
  unsigned short* wob  = ctxb + (size_t)8388608;     //  4194304
  unsigned short* vtb  = wob + (size_t)4194304;      //  8388608

  const int M = BB * SS;  // 4096

  cast_f32_bf16<<<8192, 256, 0, stream>>>(x, xb, 2097152);
  cast_f32_bf16<<<12288, 256, 0, stream>>>(wqkv, wqb, 3145728);
  cast_f32_bf16<<<4096, 256, 0, stream>>>(wout, wob, 1048576);

  {
    dim3 grid(FF / 128, M / 128);
    gemm_bf16_mfma<unsigned short><<<grid, 256, 0, stream>>>(
        xb, wqb, bqkv, qkvb, M, FF, EE);
  }
  {
    const int total = BB * SS * HH * 64;
    rotary_kernel<<<total / 256, 256, 0, stream>>>(qkvb);
  }
  {
    dim3 grid(SS / 64, DD / 64, BB * HH);
    transpose_v<<<grid, 256, 0, stream>>>(qkvb, vtb);
  }
  {
    dim3 grid(SS / ATQ, HH, BB);
    attn_mfma<<<grid, 256, 0, stream>>>(qkvb, vtb, ctxb);
  }
  {
    dim3 grid(EE / 128, M / 128);
    gemm_bf16_mfma<float><<<grid, 256, 0, stream>>>(
        ctxb, wob, bout, out, M, EE, EE);
  }
}

// Round 7
// 450.715 us; speedup vs baseline: 1.2217x; 1.0183x over previous
//
#include <hip/hip_runtime.h>
#include <math.h>

// Problem constants
#define BB 2
#define SS 2048
#define EE 2048
#define HH 16
#define DD 128
#define FF 6144   // 3*E

typedef __attribute__((ext_vector_type(8))) short short8;
typedef __attribute__((ext_vector_type(4))) float floatx4;

static __device__ __forceinline__ unsigned short f2bf(float x) {
  unsigned u = __float_as_uint(x);
  u += 0x7fffu + ((u >> 16) & 1u);
  return (unsigned short)(u >> 16);
}
static __device__ __forceinline__ float bf2f(unsigned short h) {
  return __uint_as_float((unsigned)h << 16);
}

#define GLOAD_LDS16(gp, lp)                                       \
  __builtin_amdgcn_global_load_lds(                               \
      (const __attribute__((address_space(1))) void*)(gp),        \
      (__attribute__((address_space(3))) void*)(lp), 16, 0, 0)

// ---------------------------------------------------------------------------
// fp32 -> bf16 cast (float4 in, ushort4 out)
// ---------------------------------------------------------------------------
__global__ __launch_bounds__(256) void cast_f32_bf16(
    const float* __restrict__ in, unsigned short* __restrict__ out, int n4) {
  const int i = blockIdx.x * 256 + threadIdx.x;
  if (i >= n4) return;
  const float4 v = ((const float4*)in)[i];
  ushort4 o;
  o.x = f2bf(v.x); o.y = f2bf(v.y); o.z = f2bf(v.z); o.w = f2bf(v.w);
  ((ushort4*)out)[i] = o;
}

// ---------------------------------------------------------------------------
// bf16 MFMA GEMM, double-buffered (R6 structure, unchanged)
// ---------------------------------------------------------------------------
static __device__ __forceinline__ void store_out(float* p, float v) { *p = v; }
static __device__ __forceinline__ void store_out(unsigned short* p, float v) {
  *p = f2bf(v);
}

template <typename OutT>
__global__ __launch_bounds__(256) void gemm_bf16_mfma(
    const unsigned short* __restrict__ A, const unsigned short* __restrict__ Bt,
    const float* __restrict__ bias, OutT* __restrict__ C,
    int M, int N, int K) {
  __shared__ unsigned short As[2][128][32];
  __shared__ unsigned short Bs[2][128][32];
  const int tid = threadIdx.x;
  const int L = tid & 63;
  const int w = tid >> 6;
  const int m0 = blockIdx.y * 128;
  const int n0 = blockIdx.x * 128;

  const int i0 = w * 2;
  const int lrow = L >> 2;
  const int lcol = (L & 3) * 8;
  const size_t a_off0 = (size_t)(m0 + (i0 + 0) * 16 + lrow) * K + lcol;
  const size_t a_off1 = (size_t)(m0 + (i0 + 1) * 16 + lrow) * K + lcol;
  const size_t b_off0 = (size_t)(n0 + (i0 + 0) * 16 + lrow) * K + lcol;
  const size_t b_off1 = (size_t)(n0 + (i0 + 1) * 16 + lrow) * K + lcol;

  const int wr = (w >> 1) * 64;
  const int wc = (w & 1) * 64;
  const int lane16 = L & 15;
  const int quad = L >> 4;

  floatx4 acc[4][4] = {};

  GLOAD_LDS16(A + a_off0, &As[0][(i0 + 0) * 16][0]);
  GLOAD_LDS16(A + a_off1, &As[0][(i0 + 1) * 16][0]);
  GLOAD_LDS16(Bt + b_off0, &Bs[0][(i0 + 0) * 16][0]);
  GLOAD_LDS16(Bt + b_off1, &Bs[0][(i0 + 1) * 16][0]);

  for (int k0 = 0; k0 < K; k0 += 32) {
    const int cur = (k0 >> 5) & 1;
    __syncthreads();
    if (k0 + 32 < K) {
      const int nxt = cur ^ 1;
      GLOAD_LDS16(A + a_off0 + k0 + 32, &As[nxt][(i0 + 0) * 16][0]);
      GLOAD_LDS16(A + a_off1 + k0 + 32, &As[nxt][(i0 + 1) * 16][0]);
      GLOAD_LDS16(Bt + b_off0 + k0 + 32, &Bs[nxt][(i0 + 0) * 16][0]);
      GLOAD_LDS16(Bt + b_off1 + k0 + 32, &Bs[nxt][(i0 + 1) * 16][0]);
    }

    short8 a[4], b[4];
#pragma unroll
    for (int mi = 0; mi < 4; ++mi)
      a[mi] = *(const short8*)(&As[cur][wr + mi * 16 + lane16][quad * 8]);
#pragma unroll
    for (int ni = 0; ni < 4; ++ni)
      b[ni] = *(const short8*)(&Bs[cur][wc + ni * 16 + lane16][quad * 8]);
#pragma unroll
    for (int mi = 0; mi < 4; ++mi)
#pragma unroll
      for (int ni = 0; ni < 4; ++ni)
        acc[mi][ni] = __builtin_amdgcn_mfma_f32_16x16x32_bf16(
            a[mi], b[ni], acc[mi][ni], 0, 0, 0);
  }

#pragma unroll
  for (int ni = 0; ni < 4; ++ni) {
    const int col = n0 + wc + ni * 16 + lane16;
    const float bv = bias[col];
#pragma unroll
    for (int mi = 0; mi < 4; ++mi) {
      const int row = m0 + wr + mi * 16 + quad * 4;
#pragma unroll
      for (int r = 0; r < 4; ++r)
        store_out(&C[(size_t)(row + r) * N + col], acc[mi][ni][r] + bv);
    }
  }
}

// ---------------------------------------------------------------------------
// Rotary on bf16 qkv in place. qkv layout [B][S][3][H][D] bf16.
// ---------------------------------------------------------------------------
__global__ __launch_bounds__(256) void rotary_kernel(unsigned short* __restrict__ qkv) {
  const int idx = blockIdx.x * blockDim.x + threadIdx.x;
  const int d = idx & 63;
  const int h = (idx >> 6) & (HH - 1);
  const int s = (idx >> 10) & (SS - 1);
  const int b = idx >> 21;

  const float inv_freq = powf(10000.0f, -(float)d / 64.0f);
  const float freq = (float)s * inv_freq;
  const float c = cosf(freq);
  const float sn = sinf(freq);

  const size_t base = ((size_t)b * SS + s) * FF + h * DD + d;
  unsigned short* q = qkv + base;
  unsigned short* k = qkv + base + EE;

  const float q1 = bf2f(q[0]), q2 = bf2f(q[64]);
  q[0]  = f2bf(q1 * c - q2 * sn);
  q[64] = f2bf(q2 * c + q1 * sn);
  const float k1 = bf2f(k[0]), k2 = bf2f(k[64]);
  k[0]  = f2bf(k1 * c - k2 * sn);
  k[64] = f2bf(k2 * c + k1 * sn);
}

// ---------------------------------------------------------------------------
// V transpose: qkv V slab [b][s][h][d] -> vt [b*H+h][d][s]   (bf16)
// ---------------------------------------------------------------------------
__global__ __launch_bounds__(256) void transpose_v(
    const unsigned short* __restrict__ qkv, unsigned short* __restrict__ vt) {
  __shared__ unsigned short T[64][72];
  const int t = threadIdx.x;
  const int s0 = blockIdx.x * 64;
  const int d0 = blockIdx.y * 64;
  const int bh = blockIdx.z;
  const int b = bh >> 4, h = bh & 15;
  {
    const int r = t >> 2, c = (t & 3) * 16;
    const unsigned short* src =
        qkv + ((size_t)b * SS + s0 + r) * FF + 2 * EE + h * DD + d0 + c;
    const uint4 u0 = *(const uint4*)src;
    const uint4 u1 = *(const uint4*)(src + 8);
    *(uint4*)&T[r][c] = u0;
    *(uint4*)&T[r][c + 8] = u1;
  }
  __syncthreads();
  {
    const int rr = t >> 2, cc = (t & 3) * 16;
    unsigned short vals[16];
#pragma unroll
    for (int j = 0; j < 16; ++j) vals[j] = T[cc + j][rr];
    unsigned short* dst =
        vt + (size_t)bh * DD * SS + (size_t)(d0 + rr) * SS + s0 + cc;
    *(uint4*)dst = *(uint4*)&vals[0];
    *(uint4*)(dst + 8) = *(uint4*)&vals[8];
  }
}

// ---------------------------------------------------------------------------
// MFMA flash attention, causal — S^T/O^T, double-buffered K/V, PAIRED q-tiles.
// Each block handles q-tiles (15-pi) then (pi): uniform 68 tile-iters/block,
// 256 blocks = 1/CU, no scheduling tail. Phase boundary is race-free: nkt is
// even, so prev phase's last compute reads buf 1 while the next phase's
// prologue stages buf 0; the next loop's first barrier drains it.
// ---------------------------------------------------------------------------
#define ATQ 128
#define ATK 32
#define SPAD 40  // P row stride (ushorts): 80 B, 16B-aligned
#define NQT (SS / ATQ)  // 16

__global__ __launch_bounds__(256, 2) void attn_mfma(
    const unsigned short* __restrict__ qkv,
    const unsigned short* __restrict__ vt,
    unsigned short* __restrict__ ctx) {
  __shared__ __align__(16) unsigned short Ksh[2][ATK * DD];  // [buf][kk][d]
  __shared__ __align__(16) unsigned short Vsh[2][DD * ATK];  // [buf][d][kk]
  __shared__ __align__(16) unsigned short Ssh[ATQ][SPAD];    // P [q][kk]

  const int tid = threadIdx.x;
  const int L = tid & 63;
  const int w = tid >> 6;
  const int lane16 = L & 15;
  const int quad = L >> 4;

  const int pi = blockIdx.x;  // 0..7 pair index
  const int h = blockIdx.y;
  const int b = blockIdx.z;
  const int bh = b * HH + h;
  const float scale = 0.08838834764831845f;  // 1/sqrt(128)

  // Staging addresses (b/h dependent only; shared by both phases).
  size_t koff[2], voff[2];
  int kdst[2], vdst[2];
#pragma unroll
  for (int j = 0; j < 2; ++j) {
    const int ck = j * 256 + tid;
    const int kk = ck >> 4;
    const int cgk = (ck & 15) ^ (kk & 15);
    koff[j] = ((size_t)b * SS + kk) * FF + EE + h * DD + cgk * 8;
    kdst[j] = (j * 256 + w * 64) * 8;
    const int d = ck >> 2;
    const int cgv = (ck & 3) ^ (d & 3);
    voff[j] = (size_t)bh * DD * SS + (size_t)d * SS + cgv * 8;
    vdst[j] = kdst[j];
  }

#pragma unroll 1
  for (int phase = 0; phase < 2; ++phase) {
    const int qb = phase ? pi : (NQT - 1 - pi);
    const int q0 = qb * ATQ;

    // Q frags (B-operand): lane holds Q[q0+w*32+mi*16+lane16][dc*32+quad*8+j]
    short8 qf[2][4];
#pragma unroll
    for (int mi = 0; mi < 2; ++mi) {
      const int q = q0 + w * 32 + mi * 16 + lane16;
      const unsigned short* qp =
          qkv + ((size_t)b * SS + q) * FF + h * DD + quad * 8;
#pragma unroll
      for (int dc = 0; dc < 4; ++dc)
        qf[mi][dc] = *(const short8*)(qp + dc * 32);
    }

    floatx4 acc[8][2] = {};  // O^T: row d=dt*16+quad*4+r, col q=mi*16+lane16
    float m_i[2] = {-3.0e38f, -3.0e38f};
    float l_i[2] = {0.0f, 0.0f};

    const int nkt = 4 * qb + 4;
    const int mykt = 4 * qb + w;

    // prologue: stage tile 0 -> buf 0 (safe: prev phase last read buf 1)
#pragma unroll
    for (int j = 0; j < 2; ++j) {
      GLOAD_LDS16(qkv + koff[j], &Ksh[0][kdst[j]]);
      GLOAD_LDS16(vt + voff[j], &Vsh[0][vdst[j]]);
    }

    for (int kt = 0; kt < nkt; ++kt) {
      const int cur = kt & 1;
      __syncthreads();  // drains stage(kt), issued one compute-phase ago
      if (kt + 1 < nkt) {
        const size_t ka = (size_t)(kt + 1) * ATK * FF;
        const int va = (kt + 1) * ATK;
#pragma unroll
        for (int j = 0; j < 2; ++j) {
          GLOAD_LDS16(qkv + koff[j] + ka, &Ksh[cur ^ 1][kdst[j]]);
          GLOAD_LDS16(vt + voff[j] + va, &Vsh[cur ^ 1][vdst[j]]);
        }
      }
      if (kt > mykt) continue;  // fully-masked diagonal tile for this wave
      const int k0 = kt * ATK;
      const unsigned short* Kc = Ksh[cur];
      const unsigned short* Vc = Vsh[cur];

      // --- S^T = K x Q^T : 32 kk x 32 q per wave ---
      floatx4 st[2][2] = {};
#pragma unroll
      for (int kkt = 0; kkt < 2; ++kkt) {
        const unsigned short* krow = Kc + (kkt * 16 + lane16) * 128;
#pragma unroll
        for (int dc = 0; dc < 4; ++dc) {
          const short8 kf =
              *(const short8*)(krow + ((dc * 4 + quad) ^ lane16) * 8);
#pragma unroll
          for (int mi = 0; mi < 2; ++mi)
            st[kkt][mi] = __builtin_amdgcn_mfma_f32_16x16x32_bf16(
                kf, qf[mi][dc], st[kkt][mi], 0, 0, 0);
        }
      }

      // --- scale + causal mask (only diagonal tile needs it) ---
      const bool needmask = (kt == mykt);
#pragma unroll
      for (int mi = 0; mi < 2; ++mi) {
        const int q_glob = q0 + w * 32 + mi * 16 + lane16;
#pragma unroll
        for (int kkt = 0; kkt < 2; ++kkt) {
          const int kkb = k0 + kkt * 16 + quad * 4;
#pragma unroll
          for (int r = 0; r < 4; ++r) {
            float v = st[kkt][mi][r] * scale;
            if (needmask && (kkb + r) > q_glob) v = -3.0e38f;
            st[kkt][mi][r] = v;
          }
        }
      }

      // --- online softmax per column q: 8 local values + 2 shuffles ---
      float alpha[2];
#pragma unroll
      for (int mi = 0; mi < 2; ++mi) {
        float tm = -3.0e38f;
#pragma unroll
        for (int kkt = 0; kkt < 2; ++kkt)
#pragma unroll
          for (int r = 0; r < 4; ++r) tm = fmaxf(tm, st[kkt][mi][r]);
        tm = fmaxf(tm, __shfl_xor(tm, 16));
        tm = fmaxf(tm, __shfl_xor(tm, 32));
        const float mn = fmaxf(m_i[mi], tm);
        alpha[mi] = __expf(m_i[mi] - mn);
        m_i[mi] = mn;

        float rs = 0.0f;
#pragma unroll
        for (int kkt = 0; kkt < 2; ++kkt)
#pragma unroll
          for (int r = 0; r < 4; ++r) {
            const float p = __expf(st[kkt][mi][r] - mn);
            st[kkt][mi][r] = p;
            rs += p;
          }
        rs += __shfl_xor(rs, 16);
        rs += __shfl_xor(rs, 32);
        l_i[mi] = l_i[mi] * alpha[mi] + rs;

#pragma unroll
        for (int kkt = 0; kkt < 2; ++kkt) {
          ushort4 pk;
          pk.x = f2bf(st[kkt][mi][0]);
          pk.y = f2bf(st[kkt][mi][1]);
          pk.z = f2bf(st[kkt][mi][2]);
          pk.w = f2bf(st[kkt][mi][3]);
          *(ushort4*)(&Ssh[w * 32 + mi * 16 + lane16][kkt * 16 + quad * 4]) =
              pk;
        }
      }

      // rescale O^T (alpha per-lane: col q = lane16)
#pragma unroll
      for (int dt = 0; dt < 8; ++dt)
#pragma unroll
        for (int mi = 0; mi < 2; ++mi)
#pragma unroll
          for (int r = 0; r < 4; ++r) acc[dt][mi][r] *= alpha[mi];

      // --- O^T += V^T x P^T : 128 d x 32 q, contraction 32 kk ---
      short8 pa[2];
#pragma unroll
      for (int mi = 0; mi < 2; ++mi)
        pa[mi] = *(const short8*)(&Ssh[w * 32 + mi * 16 + lane16][quad * 8]);
      const int vpos = (quad ^ (lane16 & 3)) * 8;
#pragma unroll
      for (int dt = 0; dt < 8; ++dt) {
        const short8 vf =
            *(const short8*)(Vc + (dt * 16 + lane16) * 32 + vpos);
#pragma unroll
        for (int mi = 0; mi < 2; ++mi)
          acc[dt][mi] = __builtin_amdgcn_mfma_f32_16x16x32_bf16(
              vf, pa[mi], acc[dt][mi], 0, 0, 0);
      }
    }

    // epilogue: O^T row=d=dt*16+quad*4+r, col=q=mi*16+lane16 -> ctx
#pragma unroll
    for (int mi = 0; mi < 2; ++mi) {
      const float inv = 1.0f / l_i[mi];
      const int q = q0 + w * 32 + mi * 16 + lane16;
      unsigned short* op = ctx + ((size_t)b * SS + q) * EE + h * DD + quad * 4;
#pragma unroll
      for (int dt = 0; dt < 8; ++dt) {
        ushort4 o;
        o.x = f2bf(acc[dt][mi][0] * inv);
        o.y = f2bf(acc[dt][mi][1] * inv);
        o.z = f2bf(acc[dt][mi][2] * inv);
        o.w = f2bf(acc[dt][mi][3] * inv);
        *(ushort4*)(op + dt * 16) = o;
      }
    }
  }
}

// ---------------------------------------------------------------------------
// Launch
// ---------------------------------------------------------------------------
extern "C" void kernel_launch(void* const* d_in, const int* in_sizes, int n_in,
                              void* d_out, int out_size, void* d_ws,
                              size_t ws_size, hipStream_t stream) {
  const float* x    = (const float*)d_in[0];
  const float* wqkv = (const float*)d_in[1];
  const float* bqkv = (const float*)d_in[2];
  const float* wout = (const float*)d_in[3];
  const float* bout = (const float*)d_in[4];
  float* out = (float*)d_out;

  unsigned short* qkvb = (unsigned short*)d_ws;      // 25165824 elems
  unsigned short* xb   = qkvb + (size_t)25165824;    //  8388608
  unsigned short* wqb  = xb + (size_t)8388608;       // 12582912
  unsigned short* ctxb = wqb + (size_t)12582912;     //  8388608
  unsigned short* wob  = ctxb + (size_t)8388608;     //  4194304
  unsigned short* vtb  = wob + (size_t)4194304;      //  8388608

  const int M = BB * SS;  // 4096

  cast_f32_bf16<<<8192, 256, 0, stream>>>(x, xb, 2097152);
  cast_f32_bf16<<<12288, 256, 0, stream>>>(wqkv, wqb, 3145728);
  cast_f32_bf16<<<4096, 256, 0, stream>>>(wout, wob, 1048576);

  {
    dim3 grid(FF / 128, M / 128);
    gemm_bf16_mfma<unsigned short><<<grid, 256, 0, stream>>>(
        xb, wqb, bqkv, qkvb, M, FF, EE);
  }
  {
    const int total = BB * SS * HH * 64;
    rotary_kernel<<<total / 256, 256, 0, stream>>>(qkvb);
  }
  {
    dim3 grid(SS / 64, DD / 64, BB * HH);
    transpose_v<<<grid, 256, 0, stream>>>(qkvb, vtb);
  }
  {
    dim3 grid(NQT / 2, HH, BB);  // paired q-tiles: uniform 68 iters/block
    attn_mfma<<<grid, 256, 0, stream>>>(qkvb, vtb, ctxb);
  }
  {
    dim3 grid(EE / 128, M / 128);
    gemm_bf16_mfma<float><<<grid, 256, 0, stream>>>(
        ctxb, wob, bout, out, M, EE, EE);
  }
}

// Round 8
// 441.959 us; speedup vs baseline: 1.2459x; 1.0198x over previous
//
#include <hip/hip_runtime.h>
#include <math.h>

// Problem constants
#define BB 2
#define SS 2048
#define EE 2048
#define HH 16
#define DD 128
#define FF 6144   // 3*E

typedef __attribute__((ext_vector_type(8))) short short8;
typedef __attribute__((ext_vector_type(4))) float floatx4;

static __device__ __forceinline__ unsigned short f2bf(float x) {
  unsigned u = __float_as_uint(x);
  u += 0x7fffu + ((u >> 16) & 1u);
  return (unsigned short)(u >> 16);
}
static __device__ __forceinline__ float bf2f(unsigned short h) {
  return __uint_as_float((unsigned)h << 16);
}

#define GLOAD_LDS16(gp, lp)                                       \
  __builtin_amdgcn_global_load_lds(                               \
      (const __attribute__((address_space(1))) void*)(gp),        \
      (__attribute__((address_space(3))) void*)(lp), 16, 0, 0)

// ---------------------------------------------------------------------------
// fp32 -> bf16 cast (float4 in, ushort4 out)
// ---------------------------------------------------------------------------
__global__ __launch_bounds__(256) void cast_f32_bf16(
    const float* __restrict__ in, unsigned short* __restrict__ out, int n4) {
  const int i = blockIdx.x * 256 + threadIdx.x;
  if (i >= n4) return;
  const float4 v = ((const float4*)in)[i];
  ushort4 o;
  o.x = f2bf(v.x); o.y = f2bf(v.y); o.z = f2bf(v.z); o.w = f2bf(v.w);
  ((ushort4*)out)[i] = o;
}

// ---------------------------------------------------------------------------
// bf16 MFMA GEMM, double-buffered (R6 structure, unchanged)
// ---------------------------------------------------------------------------
static __device__ __forceinline__ void store_out(float* p, float v) { *p = v; }
static __device__ __forceinline__ void store_out(unsigned short* p, float v) {
  *p = f2bf(v);
}

template <typename OutT>
__global__ __launch_bounds__(256) void gemm_bf16_mfma(
    const unsigned short* __restrict__ A, const unsigned short* __restrict__ Bt,
    const float* __restrict__ bias, OutT* __restrict__ C,
    int M, int N, int K) {
  __shared__ unsigned short As[2][128][32];
  __shared__ unsigned short Bs[2][128][32];
  const int tid = threadIdx.x;
  const int L = tid & 63;
  const int w = tid >> 6;
  const int m0 = blockIdx.y * 128;
  const int n0 = blockIdx.x * 128;

  const int i0 = w * 2;
  const int lrow = L >> 2;
  const int lcol = (L & 3) * 8;
  const size_t a_off0 = (size_t)(m0 + (i0 + 0) * 16 + lrow) * K + lcol;
  const size_t a_off1 = (size_t)(m0 + (i0 + 1) * 16 + lrow) * K + lcol;
  const size_t b_off0 = (size_t)(n0 + (i0 + 0) * 16 + lrow) * K + lcol;
  const size_t b_off1 = (size_t)(n0 + (i0 + 1) * 16 + lrow) * K + lcol;

  const int wr = (w >> 1) * 64;
  const int wc = (w & 1) * 64;
  const int lane16 = L & 15;
  const int quad = L >> 4;

  floatx4 acc[4][4] = {};

  GLOAD_LDS16(A + a_off0, &As[0][(i0 + 0) * 16][0]);
  GLOAD_LDS16(A + a_off1, &As[0][(i0 + 1) * 16][0]);
  GLOAD_LDS16(Bt + b_off0, &Bs[0][(i0 + 0) * 16][0]);
  GLOAD_LDS16(Bt + b_off1, &Bs[0][(i0 + 1) * 16][0]);

  for (int k0 = 0; k0 < K; k0 += 32) {
    const int cur = (k0 >> 5) & 1;
    __syncthreads();
    if (k0 + 32 < K) {
      const int nxt = cur ^ 1;
      GLOAD_LDS16(A + a_off0 + k0 + 32, &As[nxt][(i0 + 0) * 16][0]);
      GLOAD_LDS16(A + a_off1 + k0 + 32, &As[nxt][(i0 + 1) * 16][0]);
      GLOAD_LDS16(Bt + b_off0 + k0 + 32, &Bs[nxt][(i0 + 0) * 16][0]);
      GLOAD_LDS16(Bt + b_off1 + k0 + 32, &Bs[nxt][(i0 + 1) * 16][0]);
    }

    short8 a[4], b[4];
#pragma unroll
    for (int mi = 0; mi < 4; ++mi)
      a[mi] = *(const short8*)(&As[cur][wr + mi * 16 + lane16][quad * 8]);
#pragma unroll
    for (int ni = 0; ni < 4; ++ni)
      b[ni] = *(const short8*)(&Bs[cur][wc + ni * 16 + lane16][quad * 8]);
#pragma unroll
    for (int mi = 0; mi < 4; ++mi)
#pragma unroll
      for (int ni = 0; ni < 4; ++ni)
        acc[mi][ni] = __builtin_amdgcn_mfma_f32_16x16x32_bf16(
            a[mi], b[ni], acc[mi][ni], 0, 0, 0);
  }

#pragma unroll
  for (int ni = 0; ni < 4; ++ni) {
    const int col = n0 + wc + ni * 16 + lane16;
    const float bv = bias[col];
#pragma unroll
    for (int mi = 0; mi < 4; ++mi) {
      const int row = m0 + wr + mi * 16 + quad * 4;
#pragma unroll
      for (int r = 0; r < 4; ++r)
        store_out(&C[(size_t)(row + r) * N + col], acc[mi][ni][r] + bv);
    }
  }
}

// ---------------------------------------------------------------------------
// Rotary on bf16 qkv in place. qkv layout [B][S][3][H][D] bf16.
// ---------------------------------------------------------------------------
__global__ __launch_bounds__(256) void rotary_kernel(unsigned short* __restrict__ qkv) {
  const int idx = blockIdx.x * blockDim.x + threadIdx.x;
  const int d = idx & 63;
  const int h = (idx >> 6) & (HH - 1);
  const int s = (idx >> 10) & (SS - 1);
  const int b = idx >> 21;

  const float inv_freq = powf(10000.0f, -(float)d / 64.0f);
  const float freq = (float)s * inv_freq;
  const float c = cosf(freq);
  const float sn = sinf(freq);

  const size_t base = ((size_t)b * SS + s) * FF + h * DD + d;
  unsigned short* q = qkv + base;
  unsigned short* k = qkv + base + EE;

  const float q1 = bf2f(q[0]), q2 = bf2f(q[64]);
  q[0]  = f2bf(q1 * c - q2 * sn);
  q[64] = f2bf(q2 * c + q1 * sn);
  const float k1 = bf2f(k[0]), k2 = bf2f(k[64]);
  k[0]  = f2bf(k1 * c - k2 * sn);
  k[64] = f2bf(k2 * c + k1 * sn);
}

// ---------------------------------------------------------------------------
// V transpose: qkv V slab [b][s][h][d] -> vt [b*H+h][d][s]   (bf16)
// ---------------------------------------------------------------------------
__global__ __launch_bounds__(256) void transpose_v(
    const unsigned short* __restrict__ qkv, unsigned short* __restrict__ vt) {
  __shared__ unsigned short T[64][72];
  const int t = threadIdx.x;
  const int s0 = blockIdx.x * 64;
  const int d0 = blockIdx.y * 64;
  const int bh = blockIdx.z;
  const int b = bh >> 4, h = bh & 15;
  {
    const int r = t >> 2, c = (t & 3) * 16;
    const unsigned short* src =
        qkv + ((size_t)b * SS + s0 + r) * FF + 2 * EE + h * DD + d0 + c;
    const uint4 u0 = *(const uint4*)src;
    const uint4 u1 = *(const uint4*)(src + 8);
    *(uint4*)&T[r][c] = u0;
    *(uint4*)&T[r][c + 8] = u1;
  }
  __syncthreads();
  {
    const int rr = t >> 2, cc = (t & 3) * 16;
    unsigned short vals[16];
#pragma unroll
    for (int j = 0; j < 16; ++j) vals[j] = T[cc + j][rr];
    unsigned short* dst =
        vt + (size_t)bh * DD * SS + (size_t)(d0 + rr) * SS + s0 + cc;
    *(uint4*)dst = *(uint4*)&vals[0];
    *(uint4*)(dst + 8) = *(uint4*)&vals[8];
  }
}

// ---------------------------------------------------------------------------
// MFMA flash attention, causal — S^T/O^T, dbuf K/V, paired q-tiles,
// XCD-co-located grid: flat block id = pi*32 + (b*16+h), so all 8 pi-blocks
// sharing one (b,h)'s K/V stream land on the SAME XCD (flat%8 const in pi).
// Each XCD then holds its 4 assigned (b,h) K+V slabs (4 x 1MB) in L2 and
// re-reads hit L2 instead of L3/HBM.
// ---------------------------------------------------------------------------
#define ATQ 128
#define ATK 32
#define SPAD 40  // P row stride (ushorts): 80 B, 16B-aligned
#define NQT (SS / ATQ)  // 16

__global__ __launch_bounds__(256, 2) void attn_mfma(
    const unsigned short* __restrict__ qkv,
    const unsigned short* __restrict__ vt,
    unsigned short* __restrict__ ctx) {
  __shared__ __align__(16) unsigned short Ksh[2][ATK * DD];  // [buf][kk][d]
  __shared__ __align__(16) unsigned short Vsh[2][DD * ATK];  // [buf][d][kk]
  __shared__ __align__(16) unsigned short Ssh[ATQ][SPAD];    // P [q][kk]

  const int tid = threadIdx.x;
  const int L = tid & 63;
  const int w = tid >> 6;
  const int lane16 = L & 15;
  const int quad = L >> 4;

  // XCD-co-location decode: pi slowest, (b,h) fastest.
  const int flat = blockIdx.x;        // 0..255
  const int pi = flat >> 5;           // 0..7 pair index
  const int bh_lin = flat & 31;       // 0..31
  const int b = bh_lin >> 4;
  const int h = bh_lin & 15;
  const int bh = b * HH + h;
  const float scale = 0.08838834764831845f;  // 1/sqrt(128)

  // Staging addresses (b/h dependent only; shared by both phases).
  size_t koff[2], voff[2];
  int kdst[2], vdst[2];
#pragma unroll
  for (int j = 0; j < 2; ++j) {
    const int ck = j * 256 + tid;
    const int kk = ck >> 4;
    const int cgk = (ck & 15) ^ (kk & 15);
    koff[j] = ((size_t)b * SS + kk) * FF + EE + h * DD + cgk * 8;
    kdst[j] = (j * 256 + w * 64) * 8;
    const int d = ck >> 2;
    const int cgv = (ck & 3) ^ (d & 3);
    voff[j] = (size_t)bh * DD * SS + (size_t)d * SS + cgv * 8;
    vdst[j] = kdst[j];
  }

#pragma unroll 1
  for (int phase = 0; phase < 2; ++phase) {
    const int qb = phase ? pi : (NQT - 1 - pi);
    const int q0 = qb * ATQ;

    // Q frags (B-operand): lane holds Q[q0+w*32+mi*16+lane16][dc*32+quad*8+j]
    short8 qf[2][4];
#pragma unroll
    for (int mi = 0; mi < 2; ++mi) {
      const int q = q0 + w * 32 + mi * 16 + lane16;
      const unsigned short* qp =
          qkv + ((size_t)b * SS + q) * FF + h * DD + quad * 8;
#pragma unroll
      for (int dc = 0; dc < 4; ++dc)
        qf[mi][dc] = *(const short8*)(qp + dc * 32);
    }

    floatx4 acc[8][2] = {};  // O^T: row d=dt*16+quad*4+r, col q=mi*16+lane16
    float m_i[2] = {-3.0e38f, -3.0e38f};
    float l_i[2] = {0.0f, 0.0f};

    const int nkt = 4 * qb + 4;
    const int mykt = 4 * qb + w;

    // prologue: stage tile 0 -> buf 0 (safe: prev phase last read buf 1)
#pragma unroll
    for (int j = 0; j < 2; ++j) {
      GLOAD_LDS16(qkv + koff[j], &Ksh[0][kdst[j]]);
      GLOAD_LDS16(vt + voff[j], &Vsh[0][vdst[j]]);
    }

    for (int kt = 0; kt < nkt; ++kt) {
      const int cur = kt & 1;
      __syncthreads();  // drains stage(kt), issued one compute-phase ago
      if (kt + 1 < nkt) {
        const size_t ka = (size_t)(kt + 1) * ATK * FF;
        const int va = (kt + 1) * ATK;
#pragma unroll
        for (int j = 0; j < 2; ++j) {
          GLOAD_LDS16(qkv + koff[j] + ka, &Ksh[cur ^ 1][kdst[j]]);
          GLOAD_LDS16(vt + voff[j] + va, &Vsh[cur ^ 1][vdst[j]]);
        }
      }
      if (kt > mykt) continue;  // fully-masked diagonal tile for this wave
      const int k0 = kt * ATK;
      const unsigned short* Kc = Ksh[cur];
      const unsigned short* Vc = Vsh[cur];

      // --- S^T = K x Q^T : 32 kk x 32 q per wave ---
      floatx4 st[2][2] = {};
#pragma unroll
      for (int kkt = 0; kkt < 2; ++kkt) {
        const unsigned short* krow = Kc + (kkt * 16 + lane16) * 128;
#pragma unroll
        for (int dc = 0; dc < 4; ++dc) {
          const short8 kf =
              *(const short8*)(krow + ((dc * 4 + quad) ^ lane16) * 8);
#pragma unroll
          for (int mi = 0; mi < 2; ++mi)
            st[kkt][mi] = __builtin_amdgcn_mfma_f32_16x16x32_bf16(
                kf, qf[mi][dc], st[kkt][mi], 0, 0, 0);
        }
      }

      // --- scale + causal mask (only diagonal tile needs it) ---
      const bool needmask = (kt == mykt);
#pragma unroll
      for (int mi = 0; mi < 2; ++mi) {
        const int q_glob = q0 + w * 32 + mi * 16 + lane16;
#pragma unroll
        for (int kkt = 0; kkt < 2; ++kkt) {
          const int kkb = k0 + kkt * 16 + quad * 4;
#pragma unroll
          for (int r = 0; r < 4; ++r) {
            float v = st[kkt][mi][r] * scale;
            if (needmask && (kkb + r) > q_glob) v = -3.0e38f;
            st[kkt][mi][r] = v;
          }
        }
      }

      // --- online softmax per column q: 8 local values + 2 shuffles ---
      float alpha[2];
#pragma unroll
      for (int mi = 0; mi < 2; ++mi) {
        float tm = -3.0e38f;
#pragma unroll
        for (int kkt = 0; kkt < 2; ++kkt)
#pragma unroll
          for (int r = 0; r < 4; ++r) tm = fmaxf(tm, st[kkt][mi][r]);
        tm = fmaxf(tm, __shfl_xor(tm, 16));
        tm = fmaxf(tm, __shfl_xor(tm, 32));
        const float mn = fmaxf(m_i[mi], tm);
        alpha[mi] = __expf(m_i[mi] - mn);
        m_i[mi] = mn;

        float rs = 0.0f;
#pragma unroll
        for (int kkt = 0; kkt < 2; ++kkt)
#pragma unroll
          for (int r = 0; r < 4; ++r) {
            const float p = __expf(st[kkt][mi][r] - mn);
            st[kkt][mi][r] = p;
            rs += p;
          }
        rs += __shfl_xor(rs, 16);
        rs += __shfl_xor(rs, 32);
        l_i[mi] = l_i[mi] * alpha[mi] + rs;

#pragma unroll
        for (int kkt = 0; kkt < 2; ++kkt) {
          ushort4 pk;
          pk.x = f2bf(st[kkt][mi][0]);
          pk.y = f2bf(st[kkt][mi][1]);
          pk.z = f2bf(st[kkt][mi][2]);
          pk.w = f2bf(st[kkt][mi][3]);
          *(ushort4*)(&Ssh[w * 32 + mi * 16 + lane16][kkt * 16 + quad * 4]) =
              pk;
        }
      }

      // rescale O^T (alpha per-lane: col q = lane16)
#pragma unroll
      for (int dt = 0; dt < 8; ++dt)
#pragma unroll
        for (int mi = 0; mi < 2; ++mi)
#pragma unroll
          for (int r = 0; r < 4; ++r) acc[dt][mi][r] *= alpha[mi];

      // --- O^T += V^T x P^T : 128 d x 32 q, contraction 32 kk ---
      short8 pa[2];
#pragma unroll
      for (int mi = 0; mi < 2; ++mi)
        pa[mi] = *(const short8*)(&Ssh[w * 32 + mi * 16 + lane16][quad * 8]);
      const int vpos = (quad ^ (lane16 & 3)) * 8;
#pragma unroll
      for (int dt = 0; dt < 8; ++dt) {
        const short8 vf =
            *(const short8*)(Vc + (dt * 16 + lane16) * 32 + vpos);
#pragma unroll
        for (int mi = 0; mi < 2; ++mi)
          acc[dt][mi] = __builtin_amdgcn_mfma_f32_16x16x32_bf16(
              vf, pa[mi], acc[dt][mi], 0, 0, 0);
      }
    }

    // epilogue: O^T row=d=dt*16+quad*4+r, col=q=mi*16+lane16 -> ctx
#pragma unroll
    for (int mi = 0; mi < 2; ++mi) {
      const float inv = 1.0f / l_i[mi];
      const int q = q0 + w * 32 + mi * 16 + lane16;
      unsigned short* op = ctx + ((size_t)b * SS + q) * EE + h * DD + quad * 4;
#pragma unroll
      for (int dt = 0; dt < 8; ++dt) {
        ushort4 o;
        o.x = f2bf(acc[dt][mi][0] * inv);
        o.y = f2bf(acc[dt][mi][1] * inv);
        o.z = f2bf(acc[dt][mi][2] * inv);
        o.w = f2bf(acc[dt][mi][3] * inv);
        *(ushort4*)(op + dt * 16) = o;
      }
    }
  }
}

// ---------------------------------------------------------------------------
// Launch
// ---------------------------------------------------------------------------
extern "C" void kernel_launch(void* const* d_in, const int* in_sizes, int n_in,
                              void* d_out, int out_size, void* d_ws,
                              size_t ws_size, hipStream_t stream) {
  const float* x    = (const float*)d_in[0];
  const float* wqkv = (const float*)d_in[1];
  const float* bqkv = (const float*)d_in[2];
  const float* wout = (const float*)d_in[3];
  const float* bout = (const float*)d_in[4];
  float* out = (float*)d_out;

  unsigned short* qkvb = (unsigned short*)d_ws;      // 25165824 elems
  unsigned short* xb   = qkvb + (size_t)25165824;    //  8388608
  unsigned short* wqb  = xb + (size_t)8388608;       // 12582912
  unsigned short* ctxb = wqb + (size_t)12582912;     //  8388608
  unsigned short* wob  = ctxb + (size_t)8388608;     //  4194304
  unsigned short* vtb  = wob + (size_t)4194304;      //  8388608

  const int M = BB * SS;  // 4096

  cast_f32_bf16<<<8192, 256, 0, stream>>>(x, xb, 2097152);
  cast_f32_bf16<<<12288, 256, 0, stream>>>(wqkv, wqb, 3145728);
  cast_f32_bf16<<<4096, 256, 0, stream>>>(wout, wob, 1048576);

  {
    dim3 grid(FF / 128, M / 128);
    gemm_bf16_mfma<unsigned short><<<grid, 256, 0, stream>>>(
        xb, wqb, bqkv, qkvb, M, FF, EE);
  }
  {
    const int total = BB * SS * HH * 64;
    rotary_kernel<<<total / 256, 256, 0, stream>>>(qkvb);
  }
  {
    dim3 grid(SS / 64, DD / 64, BB * HH);
    transpose_v<<<grid, 256, 0, stream>>>(qkvb, vtb);
  }
  {
    // flat grid, XCD-co-located: flat = pi*32 + (b*16+h)
    attn_mfma<<<dim3(256), 256, 0, stream>>>(qkvb, vtb, ctxb);
  }
  {
    dim3 grid(EE / 128, M / 128);
    gemm_bf16_mfma<float><<<grid, 256, 0, stream>>>(
        ctxb, wob, bout, out, M, EE, EE);
  }
}